// Round 17
// baseline (51.959 us; speedup 1.0000x reference)
//
#include <hip/hip_runtime.h>
#include <stdint.h>

#define B_ 512
#define M_ 32
#define D_ 2048
#define Q4 128   // float4 per row per quarter (512 cols)

typedef float fvec4 __attribute__((ext_vector_type(4)));

static __device__ __forceinline__ uint32_t pk_bf16(float lo, float hi) {
    uint32_t r;
    asm("v_cvt_pk_bf16_f32 %0, %1, %2" : "=v"(r) : "v"(lo), "v"(hi));
    return r;
}
static __device__ __forceinline__ float bf_lo(uint32_t u) { return __uint_as_float(u << 16); }
static __device__ __forceinline__ float bf_hi(uint32_t u) { return __uint_as_float(u & 0xFFFF0000u); }

// 256 blocks (1/CU), 1024 threads, 2 batches per block, 4x32KB LDS quarter-buffers.
// Batch B's reads are pipelined under batch A's writes (3 of 4 quarters overlap),
// attacking the read-phase/write-phase serialization that left R14 at 51 us
// (20% above the 6.3 TB/s copy roofline for its 268 MB of fabric traffic).
__global__ __launch_bounds__(1024, 4) void ephaptic_pipe(const float* __restrict__ x,
                                                         const float* __restrict__ w,
                                                         float* __restrict__ out) {
    const int tid = threadIdx.x;
    const int b0 = blockIdx.x * 2;

    __shared__ uint32_t sx[4][M_][256];     // 4 quarter-buffers, bf16 pairs (32 KB each)
    __shared__ float sT[M_], sF[M_], sL[M_];
    __shared__ fvec4 sCA[M_], sCB[M_];

    // R-mapping: thread (m,t) covers row m, 4 float4s per quarter
    const int m = tid >> 5;
    const int t = tid & 31;
    // W-mapping: thread (rg,p4) covers col4 p4 for rows rg*4..rg*4+3
    const int p4 = tid & 127;
    const int rg = tid >> 7;

    const fvec4* wf = (const fvec4*)w;

    float psum = 0.f, first = 0.f, last = 0.f;
    fvec4 v0, v1, v2, v3;

    // issue the 4 global loads for quarter rq of batch b (then pin so they stay issued)
    auto RL = [&](int b, int rq) {
        const fvec4* row = (const fvec4*)(x + ((size_t)b * M_ + m) * (size_t)D_) + rq * Q4;
        v0 = row[t];  v1 = row[t + 32];  v2 = row[t + 64];  v3 = row[t + 96];
        asm volatile("" : "+v"(v0), "+v"(v1), "+v"(v2), "+v"(v3));
    };
    // consume: accumulate row-sum partials, capture edges, pack to LDS buf rq
    auto RS = [&](int rq) {
        psum += (v0.x+v0.y)+(v0.z+v0.w) + (v1.x+v1.y)+(v1.z+v1.w)
              + (v2.x+v2.y)+(v2.z+v2.w) + (v3.x+v3.y)+(v3.z+v3.w);
        if (rq == 0 && t == 0)  first = v0.x;   // x[m][0]
        if (rq == 3 && t == 31) last  = v3.w;   // x[m][2047]
        uint2* sr = (uint2*)sx[rq][m];
        sr[t]      = make_uint2(pk_bf16(v0.x, v0.y), pk_bf16(v0.z, v0.w));
        sr[t + 32] = make_uint2(pk_bf16(v1.x, v1.y), pk_bf16(v1.z, v1.w));
        sr[t + 64] = make_uint2(pk_bf16(v2.x, v2.y), pk_bf16(v2.z, v2.w));
        sr[t + 96] = make_uint2(pk_bf16(v3.x, v3.y), pk_bf16(v3.z, v3.w));
    };
    // butterfly the per-thread partials into sT/sF/sL
    auto SUMS = [&]() {
        float s = psum;
#pragma unroll
        for (int off = 16; off > 0; off >>= 1) s += __shfl_xor(s, off, 64);
        if (t == 0)  { sT[m] = s; sF[m] = first; }
        if (t == 31) { sL[m] = last; }
    };
    // 32x32 decay matvec -> coefficients (one wave)
    auto COEF = [&](fvec4* sC) {
        if (tid < M_) {
            const int i = tid;
            float r0 = 0.f, r1 = 0.f, r2 = 0.f;
            for (int j = 0; j < M_; ++j) {
                if (j == i) continue;
                const float dij = __expf(-0.5f * fabsf((float)(i - j)));
                const float T = sT[j];
                r0 += dij * (T - sL[j]);
                r1 += dij * T;
                r2 += dij * (T - sF[j]);
            }
            const float s = 0.1f / (float)D_;
            sC[i] = (fvec4){r0 * s, r1 * s, r2 * s, 0.f};
        }
    };
    // write quarter wq of batch b from LDS buf wq
    auto W = [&](int b, int wq, const fvec4* sC) {
        const fvec4 w0 = wf[(wq * Q4 + p4) * 3 + 0];
        const fvec4 w1 = wf[(wq * Q4 + p4) * 3 + 1];
        const fvec4 w2 = wf[(wq * Q4 + p4) * 3 + 2];
        fvec4* ob = (fvec4*)(out + (size_t)b * M_ * D_) + wq * Q4 + p4;
#pragma unroll
        for (int rr = 0; rr < 4; ++rr) {
            const int r = rg * 4 + rr;
            const fvec4 c = sC[r];
            const uint2 u = ((const uint2*)sx[wq][r])[p4];
            fvec4 o;
            o.x = bf_lo(u.x) + c.x * w0.x + c.y * w0.y + c.z * w0.z;
            o.y = bf_hi(u.x) + c.x * w0.w + c.y * w1.x + c.z * w1.y;
            o.z = bf_lo(u.y) + c.x * w1.z + c.y * w1.w + c.z * w2.x;
            o.w = bf_hi(u.y) + c.x * w2.y + c.y * w2.z + c.z * w2.w;
            __builtin_nontemporal_store(o, ob + (size_t)r * 512);
        }
    };

    // ---- batch A: read all 4 quarters, coefs
    RL(b0, 0); RS(0);
    RL(b0, 1); RS(1);
    RL(b0, 2); RS(2);
    RL(b0, 3); RS(3);
    SUMS();
    __syncthreads();
    COEF(sCA);
    __syncthreads();
    // ---- pipelined: write A quarter-by-quarter, refill freed buffers with batch B
    W(b0, 0, sCA);
    __syncthreads();
    psum = 0.f;
    RL(b0 + 1, 0); W(b0, 1, sCA); RS(0);
    __syncthreads();
    RL(b0 + 1, 1); W(b0, 2, sCA); RS(1);
    __syncthreads();
    RL(b0 + 1, 2); W(b0, 3, sCA); RS(2);
    __syncthreads();
    RL(b0 + 1, 3); RS(3);
    SUMS();
    __syncthreads();
    COEF(sCB);
    __syncthreads();
    // ---- batch B: drain writes
    W(b0 + 1, 0, sCB);
    W(b0 + 1, 1, sCB);
    W(b0 + 1, 2, sCB);
    W(b0 + 1, 3, sCB);
}

extern "C" void kernel_launch(void* const* d_in, const int* in_sizes, int n_in,
                              void* d_out, int out_size, void* d_ws, size_t ws_size,
                              hipStream_t stream) {
    const float* x = (const float*)d_in[0];
    const float* w = (const float*)d_in[1];
    float* out = (float*)d_out;
    ephaptic_pipe<<<B_ / 2, 1024, 0, stream>>>(x, w, out);
}

// Round 18
// 47.262 us; speedup vs baseline: 1.0994x; 1.0994x over previous
//
#include <hip/hip_runtime.h>
#include <stdint.h>

#define B_ 512
#define M_ 32
#define D_ 2048
#define Q4 128   // float4 per row per quarter (512 cols)

typedef float fvec4 __attribute__((ext_vector_type(4)));

static __device__ __forceinline__ uint32_t pk_bf16(float lo, float hi) {
    uint32_t r;
    asm("v_cvt_pk_bf16_f32 %0, %1, %2" : "=v"(r) : "v"(lo), "v"(hi));
    return r;
}
static __device__ __forceinline__ float bf_lo(uint32_t u) { return __uint_as_float(u << 16); }
static __device__ __forceinline__ float bf_hi(uint32_t u) { return __uint_as_float(u & 0xFFFF0000u); }

// LDS-only barrier: orders ds ops across waves but does NOT drain vmcnt --
// global loads stay in flight and nontemporal stores never block the barrier.
// (x is read-only and out is never re-read, so this is semantically sufficient;
// __syncthreads would insert s_waitcnt vmcnt(0) and serialize store retirement.)
static __device__ __forceinline__ void lds_barrier() {
    asm volatile("s_waitcnt lgkmcnt(0)" ::: "memory");
    __builtin_amdgcn_s_barrier();
}

// 256 blocks (1/CU), 1024 threads, 2 batches/block, 4x32KB LDS quarter-buffers.
// Distance-2 load prefetch via two register sets + lgkm-only barriers:
// batch B's reads fly under batch A's writes, and store retirement is never
// on the critical path.
__global__ __launch_bounds__(1024, 4) void ephaptic_pipe(const float* __restrict__ x,
                                                         const float* __restrict__ w,
                                                         float* __restrict__ out) {
    const int tid = threadIdx.x;
    const int b0 = blockIdx.x * 2;

    __shared__ uint32_t sx[4][M_][256];     // 4 quarter-buffers, bf16 pairs (32 KB each)
    __shared__ float sT[M_], sF[M_], sL[M_];
    __shared__ fvec4 sCA[M_], sCB[M_];

    // R-mapping: thread (m,t) covers row m, 4 float4s per quarter
    const int m = tid >> 5;
    const int t = tid & 31;
    // W-mapping: thread (rg,p4) covers col4 p4 for rows rg*4..rg*4+3
    const int p4 = tid & 127;
    const int rg = tid >> 7;

    const fvec4* wf = (const fvec4*)w;

    float psum = 0.f, first = 0.f, last = 0.f;
    fvec4 a0, a1, a2, a3;   // load set A (even quarters)
    fvec4 e0, e1, e2, e3;   // load set B (odd quarters)

    // issue the 4 global loads for quarter rq of batch b into the given set
    auto RL = [&](int b, int rq, fvec4& v0, fvec4& v1, fvec4& v2, fvec4& v3) {
        const fvec4* row = (const fvec4*)(x + ((size_t)b * M_ + m) * (size_t)D_) + rq * Q4;
        v0 = row[t];  v1 = row[t + 32];  v2 = row[t + 64];  v3 = row[t + 96];
    };
    // consume a set: accumulate row-sum partials, capture edges, pack to LDS buf rq
    auto RS = [&](int rq, const fvec4& v0, const fvec4& v1, const fvec4& v2, const fvec4& v3) {
        psum += (v0.x+v0.y)+(v0.z+v0.w) + (v1.x+v1.y)+(v1.z+v1.w)
              + (v2.x+v2.y)+(v2.z+v2.w) + (v3.x+v3.y)+(v3.z+v3.w);
        if (rq == 0 && t == 0)  first = v0.x;   // x[m][0]
        if (rq == 3 && t == 31) last  = v3.w;   // x[m][2047]
        uint2* sr = (uint2*)sx[rq][m];
        sr[t]      = make_uint2(pk_bf16(v0.x, v0.y), pk_bf16(v0.z, v0.w));
        sr[t + 32] = make_uint2(pk_bf16(v1.x, v1.y), pk_bf16(v1.z, v1.w));
        sr[t + 64] = make_uint2(pk_bf16(v2.x, v2.y), pk_bf16(v2.z, v2.w));
        sr[t + 96] = make_uint2(pk_bf16(v3.x, v3.y), pk_bf16(v3.z, v3.w));
    };
    auto SUMS = [&]() {
        float s = psum;
#pragma unroll
        for (int off = 16; off > 0; off >>= 1) s += __shfl_xor(s, off, 64);
        if (t == 0)  { sT[m] = s; sF[m] = first; }
        if (t == 31) { sL[m] = last; }
    };
    auto COEF = [&](fvec4* sC) {
        if (tid < M_) {
            const int i = tid;
            float r0 = 0.f, r1 = 0.f, r2 = 0.f;
            for (int j = 0; j < M_; ++j) {
                if (j == i) continue;
                const float dij = __expf(-0.5f * fabsf((float)(i - j)));
                const float T = sT[j];
                r0 += dij * (T - sL[j]);
                r1 += dij * T;
                r2 += dij * (T - sF[j]);
            }
            const float s = 0.1f / (float)D_;
            sC[i] = (fvec4){r0 * s, r1 * s, r2 * s, 0.f};
        }
    };
    // write quarter wq of batch b from LDS buf wq
    auto W = [&](int b, int wq, const fvec4* sC) {
        const fvec4 w0 = wf[(wq * Q4 + p4) * 3 + 0];
        const fvec4 w1 = wf[(wq * Q4 + p4) * 3 + 1];
        const fvec4 w2 = wf[(wq * Q4 + p4) * 3 + 2];
        fvec4* ob = (fvec4*)(out + (size_t)b * M_ * D_) + wq * Q4 + p4;
#pragma unroll
        for (int rr = 0; rr < 4; ++rr) {
            const int r = rg * 4 + rr;
            const fvec4 c = sC[r];
            const uint2 u = ((const uint2*)sx[wq][r])[p4];
            fvec4 o;
            o.x = bf_lo(u.x) + c.x * w0.x + c.y * w0.y + c.z * w0.z;
            o.y = bf_hi(u.x) + c.x * w0.w + c.y * w1.x + c.z * w1.y;
            o.z = bf_lo(u.y) + c.x * w1.z + c.y * w1.w + c.z * w2.x;
            o.w = bf_hi(u.y) + c.x * w2.y + c.y * w2.z + c.z * w2.w;
            __builtin_nontemporal_store(o, ob + (size_t)r * 512);
        }
    };

    // ---- batch A reads: 2-deep register pipeline
    RL(b0, 0, a0, a1, a2, a3);
    RL(b0, 1, e0, e1, e2, e3);
    RS(0, a0, a1, a2, a3);  RL(b0, 2, a0, a1, a2, a3);
    RS(1, e0, e1, e2, e3);  RL(b0, 3, e0, e1, e2, e3);
    RS(2, a0, a1, a2, a3);
    RS(3, e0, e1, e2, e3);
    SUMS();
    lds_barrier();
    COEF(sCA);
    lds_barrier();

    // ---- middle: write A quarter-by-quarter; batch B loads prefetched distance-2
    RL(b0 + 1, 0, a0, a1, a2, a3);  W(b0, 0, sCA);  lds_barrier();
    RL(b0 + 1, 1, e0, e1, e2, e3);  W(b0, 1, sCA);  lds_barrier();
    psum = 0.f;
    RS(0, a0, a1, a2, a3);  RL(b0 + 1, 2, a0, a1, a2, a3);  W(b0, 2, sCA);  lds_barrier();
    RS(1, e0, e1, e2, e3);  RL(b0 + 1, 3, e0, e1, e2, e3);  W(b0, 3, sCA);  lds_barrier();
    RS(2, a0, a1, a2, a3);
    RS(3, e0, e1, e2, e3);
    SUMS();
    lds_barrier();
    COEF(sCB);
    lds_barrier();

    // ---- batch B: drain writes (stores retire past endpgm)
    W(b0 + 1, 0, sCB);
    W(b0 + 1, 1, sCB);
    W(b0 + 1, 2, sCB);
    W(b0 + 1, 3, sCB);
}

extern "C" void kernel_launch(void* const* d_in, const int* in_sizes, int n_in,
                              void* d_out, int out_size, void* d_ws, size_t ws_size,
                              hipStream_t stream) {
    const float* x = (const float*)d_in[0];
    const float* w = (const float*)d_in[1];
    float* out = (float*)d_out;
    ephaptic_pipe<<<B_ / 2, 1024, 0, stream>>>(x, w, out);
}